// Round 8
// baseline (158.914 us; speedup 1.0000x reference)
//
#include <hip/hip_runtime.h>
#include <stdint.h>

#define M_TOTAL 32768   // B*T
#define NUMS    512
#define DIM     1024
#define TOPK    33

typedef __bf16 bf16_t;
typedef bf16_t bf16x8 __attribute__((ext_vector_type(8)));
typedef float  f32x4  __attribute__((ext_vector_type(4)));
typedef unsigned short ushort_t;

__device__ __forceinline__ ushort_t f2bf(float f) {
    union { float f; uint32_t u; } x; x.f = f;
    uint32_t r = x.u + 0x7FFFu + ((x.u >> 16) & 1u);
    return (ushort_t)(r >> 16);
}
__device__ __forceinline__ float bf2f(uint32_t u) {
    union { uint32_t u; float f; } x; x.u = u << 16;
    return x.f;
}

// global_load_lds: wave-uniform LDS base (HW adds lane*16), per-lane global src
#define GLDS16(g, l) __builtin_amdgcn_global_load_lds( \
    (const __attribute__((address_space(1))) void*)(g), \
    (__attribute__((address_space(3))) void*)(l), 16, 0, 0)

// ---------------------------------------------------------------------------
// prep: mem fp32 [512][1024] -> memB bf16 [512][1024] and memT bf16 [1024][512]
// ---------------------------------------------------------------------------
__global__ void prep_kernel(const float* __restrict__ mem,
                            ushort_t* __restrict__ memB,
                            ushort_t* __restrict__ memT) {
    __shared__ float tile[32][33];
    const int bi = blockIdx.x;      // 0..15
    const int bj = blockIdx.y;      // 0..31
    const int t  = threadIdx.x;     // 256
    const int r  = t >> 3;
    const int c4 = (t & 7) * 4;

    const float4 v = *(const float4*)(mem + (size_t)(bi * 32 + r) * DIM + bj * 32 + c4);
    ushort4 b;
    b.x = f2bf(v.x); b.y = f2bf(v.y); b.z = f2bf(v.z); b.w = f2bf(v.w);
    *(ushort4*)(memB + (size_t)(bi * 32 + r) * DIM + bj * 32 + c4) = b;
    tile[r][c4 + 0] = v.x; tile[r][c4 + 1] = v.y;
    tile[r][c4 + 2] = v.z; tile[r][c4 + 3] = v.w;
    __syncthreads();
    ushort4 o;
    o.x = f2bf(tile[c4 + 0][r]); o.y = f2bf(tile[c4 + 1][r]);
    o.z = f2bf(tile[c4 + 2][r]); o.w = f2bf(tile[c4 + 3][r]);
    *(ushort4*)(memT + (size_t)(bj * 32 + r) * NUMS + bi * 32 + c4) = o;
}

// ---------------------------------------------------------------------------
// G1 (pure GEMM + sigmoid): att = sigmoid(data @ memB^T / 32), bf16 store.
// g2-clone: 128x128, BK=64, 256 thr = 4 waves (2x2), wave tile 64x64,
// dbuf 64KB LDS -> 2 blocks/CU. A fp32 reg-staged + cvt (4 passes x 32 rows);
// B via GLDS. Grid 1024; XCD swizzle n-fastest: each XCD gets 32 m x 4 n so
// each A-panel is fetched by exactly one XCD.
// LDS: A0@0(16K) A1@16384 B0@32768 B1@49152.
// 128B rows, 8 slots: LDS slot s of row r holds global chunk s^(r&7).
// ---------------------------------------------------------------------------
__global__ __launch_bounds__(256, 2)
void g1_kernel(const float* __restrict__ data,
               const ushort_t* __restrict__ memB,
               ushort_t* __restrict__ att) {
    __shared__ __align__(16) unsigned char smem[65536];
    const int t    = threadIdx.x;
    const int lane = t & 63;
    const int wid  = t >> 6;      // 0..3
    const int wr   = wid >> 1;    // 0..1
    const int wc   = wid & 1;     // 0..1
    // bijective XCD swizzle; n fastest within an XCD's 128-block chunk
    const int wg = (blockIdx.x & 7) * 128 + (blockIdx.x >> 3);
    const int m0 = (wg >> 2) * 128;
    const int n0 = (wg & 3) * 128;

    f32x4 zero = {0.f, 0.f, 0.f, 0.f};
    f32x4 acc[4][4];
#pragma unroll
    for (int m = 0; m < 4; ++m)
#pragma unroll
        for (int n = 0; n < 4; ++n) acc[m][n] = zero;

    // ---- A staging (fp32->bf16): thread -> row (t>>3)+32p, chunk t&7; 4 passes
    const int arow = t >> 3;                       // 0..31
    const int asl  = t & 7;                        // LDS slot
    const int ach  = asl ^ (arow & 7);             // global chunk ((arow+32p)&7 == arow&7)
    const float* aSrc = data + (size_t)(m0 + arow) * DIM + ach * 8;
    const int aWOff = arow * 128 + asl * 16;       // + p*4096, + buf*16384

    // ---- B staging (GLDS): wave covers 32 rows, 4 GLDS x 8 rows
    const int srcoff = (((lane & 7) ^ (lane >> 3)) & 7) * 8;
    const ushort_t* bS = memB + (size_t)(n0 + wid * 32 + (lane >> 3)) * DIM + srcoff;

#define G1_STAGE(K0_, BUF_)                                                     \
    {                                                                           \
        /* B async */                                                           \
        unsigned char* db = smem + 32768 + ((BUF_) ? 16384 : 0)                 \
                          + wid * 4096 + lane * 16;                             \
        const ushort_t* sb = bS + (K0_);                                        \
        GLDS16(sb,            db);        GLDS16(sb +  8 * DIM, db + 1024);     \
        GLDS16(sb + 16 * DIM, db + 2048); GLDS16(sb + 24 * DIM, db + 3072);     \
        /* A: 4 passes of 32 rows */                                            \
        _Pragma("unroll") for (int p = 0; p < 4; ++p) {                         \
            const float* as = aSrc + (size_t)p * 32 * DIM + (K0_);              \
            const float4 v0 = *(const float4*)as;                               \
            const float4 v1 = *(const float4*)(as + 4);                         \
            bf16x8 cv;                                                          \
            cv[0] = (bf16_t)v0.x; cv[1] = (bf16_t)v0.y;                         \
            cv[2] = (bf16_t)v0.z; cv[3] = (bf16_t)v0.w;                         \
            cv[4] = (bf16_t)v1.x; cv[5] = (bf16_t)v1.y;                         \
            cv[6] = (bf16_t)v1.z; cv[7] = (bf16_t)v1.w;                         \
            *(bf16x8*)(smem + ((BUF_) ? 16384 : 0) + p * 4096 + aWOff) = cv;    \
        }                                                                       \
    }

    G1_STAGE(0, 0)
    __syncthreads();

    for (int tt = 0; tt < 16; ++tt) {
        if (tt < 15) {
            if ((tt & 1) == 0) G1_STAGE((tt + 1) * 64, 1)
            else               G1_STAGE((tt + 1) * 64, 0)
        }
        const unsigned char* ab = smem + ((tt & 1) ? 16384 : 0);
        const unsigned char* bb = ab + 32768;
#pragma unroll
        for (int ki = 0; ki < 2; ++ki) {
            const int ch = ki * 4 + (lane >> 4);
            bf16x8 af[4], bfr[4];
#pragma unroll
            for (int m = 0; m < 4; ++m) {
                const int row = wr * 64 + m * 16 + (lane & 15);
                af[m] = *(const bf16x8*)(ab + row * 128 + ((ch ^ (row & 7)) << 4));
            }
#pragma unroll
            for (int n = 0; n < 4; ++n) {
                const int col = wc * 64 + n * 16 + (lane & 15);
                bfr[n] = *(const bf16x8*)(bb + col * 128 + ((ch ^ (col & 7)) << 4));
            }
#pragma unroll
            for (int m = 0; m < 4; ++m)
#pragma unroll
                for (int n = 0; n < 4; ++n)
                    acc[m][n] = __builtin_amdgcn_mfma_f32_16x16x32_bf16(
                        af[m], bfr[n], acc[m][n], 0, 0, 0);
        }
        __syncthreads();
    }
#undef G1_STAGE

    // ---- epilogue: sigmoid -> bf16 att tile [128][128] in LDS, coalesced store
    ushort_t* lAtt = (ushort_t*)smem;    // 32KB over A-buffers; safe after barrier
#pragma unroll
    for (int m = 0; m < 4; ++m)
#pragma unroll
        for (int n = 0; n < 4; ++n)
#pragma unroll
            for (int reg = 0; reg < 4; ++reg) {
                const int row = wr * 64 + m * 16 + (lane >> 4) * 4 + reg;
                const int col = wc * 64 + n * 16 + (lane & 15);
                const float x = acc[m][n][reg] * 0.03125f;   // /sqrt(1024)
                const float s = 1.0f / (1.0f + __expf(-x));
                lAtt[row * 128 + col] = f2bf(s);
            }
    __syncthreads();
    {
        const uint4* lsrc = (const uint4*)lAtt;   // 2048 uint4, 16 per row
#pragma unroll
        for (int i = 0; i < 8; ++i) {
            const int idx = i * 256 + t;
            const int r   = idx >> 4;
            const int c16 = idx & 15;
            *(uint4*)(att + (size_t)(m0 + r) * 512 + n0 + c16 * 8) = lsrc[idx];
        }
    }
}

// ---------------------------------------------------------------------------
// topk: temporal[row] = mean of top-33 of att[row][:] via ballot radix-select
// (sigmoid outputs positive -> bf16 codes monotone). 4 waves, 8 rows/wave.
// ---------------------------------------------------------------------------
__global__ __launch_bounds__(256, 8)
void topk_kernel(const ushort_t* __restrict__ att,
                 float* __restrict__ temporal) {
    const int t    = threadIdx.x;
    const int lane = t & 63;
    const int wid  = t >> 6;
    const int base = blockIdx.x * 32 + wid * 8;

    for (int ri = 0; ri < 8; ++ri) {
        const int row = base + ri;
        const uint4 rv = *(const uint4*)(att + (size_t)row * 512 + lane * 8);
        uint32_t u[8];
        u[0] = rv.x & 0xFFFFu; u[1] = rv.x >> 16;
        u[2] = rv.y & 0xFFFFu; u[3] = rv.y >> 16;
        u[4] = rv.z & 0xFFFFu; u[5] = rv.z >> 16;
        u[6] = rv.w & 0xFFFFu; u[7] = rv.w >> 16;
        uint32_t tc = 0;
#pragma unroll
        for (int b = 14; b >= 0; --b) {
            const uint32_t cand = tc | (1u << b);
            int c = 0;
#pragma unroll
            for (int j = 0; j < 8; ++j)
                c += __popcll(__ballot(u[j] >= cand));
            if (c >= TOPK) tc = cand;
        }
        float sgt = 0.f; int cgt = 0;
#pragma unroll
        for (int j = 0; j < 8; ++j) {
            if (u[j] > tc) { sgt += bf2f(u[j]); cgt++; }
        }
#pragma unroll
        for (int off = 32; off >= 1; off >>= 1) {
            sgt += __shfl_xor(sgt, off);
            cgt += __shfl_xor(cgt, off);
        }
        if (lane == 0)
            temporal[row] = (sgt + (float)(TOPK - cgt) * bf2f(tc)) * (1.0f / 33.0f);
    }
}

// ---------------------------------------------------------------------------
// G2: aug = att bf16 @ memT^T. 128x128, BK=64, 4 waves, double-buffered,
// XCD-swizzled. (unchanged — ~30us)
// ---------------------------------------------------------------------------
__global__ __launch_bounds__(256, 2)
void g2_kernel(const ushort_t* __restrict__ att,
               const ushort_t* __restrict__ memT,
               float* __restrict__ aug) {
    __shared__ __align__(16) unsigned char smem[65536];
    const int t    = threadIdx.x;
    const int lane = t & 63;
    const int wid  = t >> 6;
    const int wr   = wid >> 1;
    const int wc   = wid & 1;
    const int wg = (blockIdx.x & 7) * 256 + (blockIdx.x >> 3);
    const int m0 = (wg >> 3) * 128;
    const int n0 = (wg & 7) * 128;

    f32x4 zero = {0.f, 0.f, 0.f, 0.f};
    f32x4 acc[4][4];
#pragma unroll
    for (int m = 0; m < 4; ++m)
#pragma unroll
        for (int n = 0; n < 4; ++n) acc[m][n] = zero;

    const int srcoff = (((lane & 7) ^ (lane >> 3)) & 7) * 8;
    const ushort_t* aS = att  + (size_t)(m0 + wid * 32 + (lane >> 3)) * 512 + srcoff;
    const ushort_t* bS = memT + (size_t)(n0 + wid * 32 + (lane >> 3)) * 512 + srcoff;

#define G2_STAGE(K0_, PAR_)                                                     \
    {                                                                           \
        unsigned char* da = smem + ((PAR_) ? 16384 : 0) + wid * 4096 + lane * 16; \
        unsigned char* db = da + 32768;                                         \
        const ushort_t* sa = aS + (K0_);                                        \
        const ushort_t* sb = bS + (K0_);                                        \
        GLDS16(sa,            da);        GLDS16(sb,            db);            \
        GLDS16(sa +  8 * 512, da + 1024); GLDS16(sb +  8 * 512, db + 1024);     \
        GLDS16(sa + 16 * 512, da + 2048); GLDS16(sb + 16 * 512, db + 2048);     \
        GLDS16(sa + 24 * 512, da + 3072); GLDS16(sb + 24 * 512, db + 3072);     \
    }

    G2_STAGE(0, 0)
    __syncthreads();

    for (int tt = 0; tt < 8; ++tt) {
        if (tt < 7) {
            if ((tt & 1) == 0) G2_STAGE((tt + 1) * 64, 1)
            else               G2_STAGE((tt + 1) * 64, 0)
        }
        const unsigned char* ab = smem + ((tt & 1) ? 16384 : 0);
        const unsigned char* bb = ab + 32768;
#pragma unroll
        for (int ki = 0; ki < 2; ++ki) {
            const int ch = ki * 4 + (lane >> 4);
            bf16x8 af[4], bfr[4];
#pragma unroll
            for (int m = 0; m < 4; ++m) {
                const int row = wr * 64 + m * 16 + (lane & 15);
                af[m] = *(const bf16x8*)(ab + row * 128 + ((ch ^ (row & 7)) << 4));
            }
#pragma unroll
            for (int n = 0; n < 4; ++n) {
                const int col = wc * 64 + n * 16 + (lane & 15);
                bfr[n] = *(const bf16x8*)(bb + col * 128 + ((ch ^ (col & 7)) << 4));
            }
#pragma unroll
            for (int m = 0; m < 4; ++m)
#pragma unroll
                for (int n = 0; n < 4; ++n)
                    acc[m][n] = __builtin_amdgcn_mfma_f32_16x16x32_bf16(
                        af[m], bfr[n], acc[m][n], 0, 0, 0);
        }
        __syncthreads();
    }
#undef G2_STAGE

#pragma unroll
    for (int m = 0; m < 4; ++m)
#pragma unroll
        for (int n = 0; n < 4; ++n)
#pragma unroll
            for (int reg = 0; reg < 4; ++reg) {
                const int row = m0 + wr * 64 + m * 16 + (lane >> 4) * 4 + reg;
                const int col = n0 + wc * 64 + n * 16 + (lane & 15);
                aug[(size_t)row * DIM + col] = acc[m][n][reg];
            }
}

// ---------------------------------------------------------------------------
extern "C" void kernel_launch(void* const* d_in, const int* in_sizes, int n_in,
                              void* d_out, int out_size, void* d_ws, size_t ws_size,
                              hipStream_t stream) {
    const float* data = (const float*)d_in[0];   // [16,2048,1024]
    const float* mem  = (const float*)d_in[1];   // [512,1024]
    float* temporal = (float*)d_out;             // [32768]
    float* aug      = (float*)d_out + M_TOTAL;   // [32768,1024]

    ushort_t* memB = (ushort_t*)d_ws;                    // 512*1024 bf16 (1MB)
    ushort_t* memT = memB + (size_t)NUMS * DIM;          // 1024*512 bf16 (1MB)
    ushort_t* attw = memT + (size_t)DIM * NUMS;          // 32768*512 bf16 (32MB)

    prep_kernel<<<dim3(16, 32), 256, 0, stream>>>(mem, memB, memT);
    g1_kernel<<<(M_TOTAL / 128) * (NUMS / 128), 256, 0, stream>>>(data, memB, attw);
    topk_kernel<<<M_TOTAL / 32, 256, 0, stream>>>(attw, temporal);
    g2_kernel<<<(M_TOTAL / 128) * (DIM / 128), 256, 0, stream>>>(attw, memT, aug);
}

// Round 9
// 151.813 us; speedup vs baseline: 1.0468x; 1.0468x over previous
//
#include <hip/hip_runtime.h>
#include <stdint.h>

#define M_TOTAL 32768   // B*T
#define NUMS    512
#define DIM     1024
#define TOPK    33

typedef __bf16 bf16_t;
typedef bf16_t bf16x8 __attribute__((ext_vector_type(8)));
typedef float  f32x4  __attribute__((ext_vector_type(4)));
typedef unsigned short ushort_t;

__device__ __forceinline__ ushort_t f2bf(float f) {
    union { float f; uint32_t u; } x; x.f = f;
    uint32_t r = x.u + 0x7FFFu + ((x.u >> 16) & 1u);
    return (ushort_t)(r >> 16);
}
__device__ __forceinline__ float bf2f(uint32_t u) {
    union { uint32_t u; float f; } x; x.u = u << 16;
    return x.f;
}

// global_load_lds: wave-uniform LDS base (HW adds lane*16), per-lane global src
#define GLDS16(g, l) __builtin_amdgcn_global_load_lds( \
    (const __attribute__((address_space(1))) void*)(g), \
    (__attribute__((address_space(3))) void*)(l), 16, 0, 0)

// ---------------------------------------------------------------------------
// cvt: data fp32 [32768][1024] -> dataB bf16 (streaming, vectorized).
// 2048 blocks x 256 thr x 8 elems x 8 iters = 33.5M elems.
// ---------------------------------------------------------------------------
__global__ __launch_bounds__(256)
void cvt_kernel(const float* __restrict__ in, ushort_t* __restrict__ out) {
    const size_t stride = (size_t)2048 * 256 * 8;
    size_t i = ((size_t)blockIdx.x * 256 + threadIdx.x) * 8;
#pragma unroll
    for (int it = 0; it < 8; ++it, i += stride) {
        const float4 v0 = *(const float4*)(in + i);
        const float4 v1 = *(const float4*)(in + i + 4);
        union { ushort_t us[8]; uint4 v; } pk;
        pk.us[0] = f2bf(v0.x); pk.us[1] = f2bf(v0.y);
        pk.us[2] = f2bf(v0.z); pk.us[3] = f2bf(v0.w);
        pk.us[4] = f2bf(v1.x); pk.us[5] = f2bf(v1.y);
        pk.us[6] = f2bf(v1.z); pk.us[7] = f2bf(v1.w);
        *(uint4*)(out + i) = pk.v;
    }
}

// ---------------------------------------------------------------------------
// prep: mem fp32 [512][1024] -> memB bf16 [512][1024] and memT bf16 [1024][512]
// ---------------------------------------------------------------------------
__global__ void prep_kernel(const float* __restrict__ mem,
                            ushort_t* __restrict__ memB,
                            ushort_t* __restrict__ memT) {
    __shared__ float tile[32][33];
    const int bi = blockIdx.x;      // 0..15
    const int bj = blockIdx.y;      // 0..31
    const int t  = threadIdx.x;     // 256
    const int r  = t >> 3;
    const int c4 = (t & 7) * 4;

    const float4 v = *(const float4*)(mem + (size_t)(bi * 32 + r) * DIM + bj * 32 + c4);
    ushort4 b;
    b.x = f2bf(v.x); b.y = f2bf(v.y); b.z = f2bf(v.z); b.w = f2bf(v.w);
    *(ushort4*)(memB + (size_t)(bi * 32 + r) * DIM + bj * 32 + c4) = b;
    tile[r][c4 + 0] = v.x; tile[r][c4 + 1] = v.y;
    tile[r][c4 + 2] = v.z; tile[r][c4 + 3] = v.w;
    __syncthreads();
    ushort4 o;
    o.x = f2bf(tile[c4 + 0][r]); o.y = f2bf(tile[c4 + 1][r]);
    o.z = f2bf(tile[c4 + 2][r]); o.w = f2bf(tile[c4 + 3][r]);
    *(ushort4*)(memT + (size_t)(bj * 32 + r) * NUMS + bi * 32 + c4) = o;
}

// ---------------------------------------------------------------------------
// G1' (exact g2-clone, bf16 inputs): att = sigmoid(dataB @ memB^T / 32).
// 128x128, BK=64, 16 K-steps, 256 thr = 4 waves (2x2), wave tile 64x64,
// dbuf 64KB LDS -> 2 blocks/CU, both operands via GLDS.
// Grid 1024; XCD swizzle n-fastest (A-panel shared within one XCD).
// LDS: A0@0(16K) A1@16384 B0@32768 B1@49152.
// 128B rows, 8 slots: LDS slot s of row r holds global chunk s^(r&7).
// ---------------------------------------------------------------------------
__global__ __launch_bounds__(256, 2)
void g1_kernel(const ushort_t* __restrict__ dataB,
               const ushort_t* __restrict__ memB,
               ushort_t* __restrict__ att) {
    __shared__ __align__(16) unsigned char smem[65536];
    const int t    = threadIdx.x;
    const int lane = t & 63;
    const int wid  = t >> 6;      // 0..3
    const int wr   = wid >> 1;    // 0..1
    const int wc   = wid & 1;     // 0..1
    const int wg = (blockIdx.x & 7) * 128 + (blockIdx.x >> 3);
    const int m0 = (wg >> 2) * 128;
    const int n0 = (wg & 3) * 128;

    f32x4 zero = {0.f, 0.f, 0.f, 0.f};
    f32x4 acc[4][4];
#pragma unroll
    for (int m = 0; m < 4; ++m)
#pragma unroll
        for (int n = 0; n < 4; ++n) acc[m][n] = zero;

    const int srcoff = (((lane & 7) ^ (lane >> 3)) & 7) * 8;
    const ushort_t* aS = dataB + (size_t)(m0 + wid * 32 + (lane >> 3)) * DIM + srcoff;
    const ushort_t* bS = memB  + (size_t)(n0 + wid * 32 + (lane >> 3)) * DIM + srcoff;

#define G1_STAGE(K0_, BUF_)                                                     \
    {                                                                           \
        unsigned char* da = smem + ((BUF_) ? 16384 : 0) + wid * 4096 + lane * 16; \
        unsigned char* db = da + 32768;                                         \
        const ushort_t* sa = aS + (K0_);                                        \
        const ushort_t* sb = bS + (K0_);                                        \
        GLDS16(sa,            da);        GLDS16(sb,            db);            \
        GLDS16(sa +  8 * DIM, da + 1024); GLDS16(sb +  8 * DIM, db + 1024);     \
        GLDS16(sa + 16 * DIM, da + 2048); GLDS16(sb + 16 * DIM, db + 2048);     \
        GLDS16(sa + 24 * DIM, da + 3072); GLDS16(sb + 24 * DIM, db + 3072);     \
    }

    G1_STAGE(0, 0)
    __syncthreads();

    for (int tt = 0; tt < 16; ++tt) {
        if (tt < 15) {
            if ((tt & 1) == 0) G1_STAGE((tt + 1) * 64, 1)
            else               G1_STAGE((tt + 1) * 64, 0)
        }
        const unsigned char* ab = smem + ((tt & 1) ? 16384 : 0);
        const unsigned char* bb = ab + 32768;
#pragma unroll
        for (int ki = 0; ki < 2; ++ki) {
            const int ch = ki * 4 + (lane >> 4);
            bf16x8 af[4], bfr[4];
#pragma unroll
            for (int m = 0; m < 4; ++m) {
                const int row = wr * 64 + m * 16 + (lane & 15);
                af[m] = *(const bf16x8*)(ab + row * 128 + ((ch ^ (row & 7)) << 4));
            }
#pragma unroll
            for (int n = 0; n < 4; ++n) {
                const int col = wc * 64 + n * 16 + (lane & 15);
                bfr[n] = *(const bf16x8*)(bb + col * 128 + ((ch ^ (col & 7)) << 4));
            }
#pragma unroll
            for (int m = 0; m < 4; ++m)
#pragma unroll
                for (int n = 0; n < 4; ++n)
                    acc[m][n] = __builtin_amdgcn_mfma_f32_16x16x32_bf16(
                        af[m], bfr[n], acc[m][n], 0, 0, 0);
        }
        __syncthreads();
    }
#undef G1_STAGE

    // ---- epilogue: sigmoid -> bf16 att tile [128][128] in LDS, coalesced store
    ushort_t* lAtt = (ushort_t*)smem;
#pragma unroll
    for (int m = 0; m < 4; ++m)
#pragma unroll
        for (int n = 0; n < 4; ++n)
#pragma unroll
            for (int reg = 0; reg < 4; ++reg) {
                const int row = wr * 64 + m * 16 + (lane >> 4) * 4 + reg;
                const int col = wc * 64 + n * 16 + (lane & 15);
                const float x = acc[m][n][reg] * 0.03125f;   // /sqrt(1024)
                const float s = 1.0f / (1.0f + __expf(-x));
                lAtt[row * 128 + col] = f2bf(s);
            }
    __syncthreads();
    {
        const uint4* lsrc = (const uint4*)lAtt;
#pragma unroll
        for (int i = 0; i < 8; ++i) {
            const int idx = i * 256 + t;
            const int r   = idx >> 4;
            const int c16 = idx & 15;
            *(uint4*)(att + (size_t)(m0 + r) * 512 + n0 + c16 * 8) = lsrc[idx];
        }
    }
}

// ---------------------------------------------------------------------------
// topk: temporal[row] = mean of top-33 of att[row][:] via ballot radix-select
// ---------------------------------------------------------------------------
__global__ __launch_bounds__(256, 8)
void topk_kernel(const ushort_t* __restrict__ att,
                 float* __restrict__ temporal) {
    const int t    = threadIdx.x;
    const int lane = t & 63;
    const int wid  = t >> 6;
    const int base = blockIdx.x * 32 + wid * 8;

    for (int ri = 0; ri < 8; ++ri) {
        const int row = base + ri;
        const uint4 rv = *(const uint4*)(att + (size_t)row * 512 + lane * 8);
        uint32_t u[8];
        u[0] = rv.x & 0xFFFFu; u[1] = rv.x >> 16;
        u[2] = rv.y & 0xFFFFu; u[3] = rv.y >> 16;
        u[4] = rv.z & 0xFFFFu; u[5] = rv.z >> 16;
        u[6] = rv.w & 0xFFFFu; u[7] = rv.w >> 16;
        uint32_t tc = 0;
#pragma unroll
        for (int b = 14; b >= 0; --b) {
            const uint32_t cand = tc | (1u << b);
            int c = 0;
#pragma unroll
            for (int j = 0; j < 8; ++j)
                c += __popcll(__ballot(u[j] >= cand));
            if (c >= TOPK) tc = cand;
        }
        float sgt = 0.f; int cgt = 0;
#pragma unroll
        for (int j = 0; j < 8; ++j) {
            if (u[j] > tc) { sgt += bf2f(u[j]); cgt++; }
        }
#pragma unroll
        for (int off = 32; off >= 1; off >>= 1) {
            sgt += __shfl_xor(sgt, off);
            cgt += __shfl_xor(cgt, off);
        }
        if (lane == 0)
            temporal[row] = (sgt + (float)(TOPK - cgt) * bf2f(tc)) * (1.0f / 33.0f);
    }
}

// ---------------------------------------------------------------------------
// G2: aug = att bf16 @ memT^T. 128x128, BK=64, 4 waves, double-buffered,
// XCD-swizzled. (unchanged)
// ---------------------------------------------------------------------------
__global__ __launch_bounds__(256, 2)
void g2_kernel(const ushort_t* __restrict__ att,
               const ushort_t* __restrict__ memT,
               float* __restrict__ aug) {
    __shared__ __align__(16) unsigned char smem[65536];
    const int t    = threadIdx.x;
    const int lane = t & 63;
    const int wid  = t >> 6;
    const int wr   = wid >> 1;
    const int wc   = wid & 1;
    const int wg = (blockIdx.x & 7) * 256 + (blockIdx.x >> 3);
    const int m0 = (wg >> 3) * 128;
    const int n0 = (wg & 7) * 128;

    f32x4 zero = {0.f, 0.f, 0.f, 0.f};
    f32x4 acc[4][4];
#pragma unroll
    for (int m = 0; m < 4; ++m)
#pragma unroll
        for (int n = 0; n < 4; ++n) acc[m][n] = zero;

    const int srcoff = (((lane & 7) ^ (lane >> 3)) & 7) * 8;
    const ushort_t* aS = att  + (size_t)(m0 + wid * 32 + (lane >> 3)) * 512 + srcoff;
    const ushort_t* bS = memT + (size_t)(n0 + wid * 32 + (lane >> 3)) * 512 + srcoff;

#define G2_STAGE(K0_, PAR_)                                                     \
    {                                                                           \
        unsigned char* da = smem + ((PAR_) ? 16384 : 0) + wid * 4096 + lane * 16; \
        unsigned char* db = da + 32768;                                         \
        const ushort_t* sa = aS + (K0_);                                        \
        const ushort_t* sb = bS + (K0_);                                        \
        GLDS16(sa,            da);        GLDS16(sb,            db);            \
        GLDS16(sa +  8 * 512, da + 1024); GLDS16(sb +  8 * 512, db + 1024);     \
        GLDS16(sa + 16 * 512, da + 2048); GLDS16(sb + 16 * 512, db + 2048);     \
        GLDS16(sa + 24 * 512, da + 3072); GLDS16(sb + 24 * 512, db + 3072);     \
    }

    G2_STAGE(0, 0)
    __syncthreads();

    for (int tt = 0; tt < 8; ++tt) {
        if (tt < 7) {
            if ((tt & 1) == 0) G2_STAGE((tt + 1) * 64, 1)
            else               G2_STAGE((tt + 1) * 64, 0)
        }
        const unsigned char* ab = smem + ((tt & 1) ? 16384 : 0);
        const unsigned char* bb = ab + 32768;
#pragma unroll
        for (int ki = 0; ki < 2; ++ki) {
            const int ch = ki * 4 + (lane >> 4);
            bf16x8 af[4], bfr[4];
#pragma unroll
            for (int m = 0; m < 4; ++m) {
                const int row = wr * 64 + m * 16 + (lane & 15);
                af[m] = *(const bf16x8*)(ab + row * 128 + ((ch ^ (row & 7)) << 4));
            }
#pragma unroll
            for (int n = 0; n < 4; ++n) {
                const int col = wc * 64 + n * 16 + (lane & 15);
                bfr[n] = *(const bf16x8*)(bb + col * 128 + ((ch ^ (col & 7)) << 4));
            }
#pragma unroll
            for (int m = 0; m < 4; ++m)
#pragma unroll
                for (int n = 0; n < 4; ++n)
                    acc[m][n] = __builtin_amdgcn_mfma_f32_16x16x32_bf16(
                        af[m], bfr[n], acc[m][n], 0, 0, 0);
        }
        __syncthreads();
    }
#undef G2_STAGE

#pragma unroll
    for (int m = 0; m < 4; ++m)
#pragma unroll
        for (int n = 0; n < 4; ++n)
#pragma unroll
            for (int reg = 0; reg < 4; ++reg) {
                const int row = m0 + wr * 64 + m * 16 + (lane >> 4) * 4 + reg;
                const int col = n0 + wc * 64 + n * 16 + (lane & 15);
                aug[(size_t)row * DIM + col] = acc[m][n][reg];
            }
}

// ---------------------------------------------------------------------------
extern "C" void kernel_launch(void* const* d_in, const int* in_sizes, int n_in,
                              void* d_out, int out_size, void* d_ws, size_t ws_size,
                              hipStream_t stream) {
    const float* data = (const float*)d_in[0];   // [16,2048,1024]
    const float* mem  = (const float*)d_in[1];   // [512,1024]
    float* temporal = (float*)d_out;             // [32768]
    float* aug      = (float*)d_out + M_TOTAL;   // [32768,1024] fp32 (128MB)

    ushort_t* memB = (ushort_t*)d_ws;                    // 1MB
    ushort_t* memT = memB + (size_t)NUMS * DIM;          // 1MB
    ushort_t* attw = memT + (size_t)DIM * NUMS;          // 32MB
    // dataB bf16 (64MB) lives in the aug output region; consumed by g1 before
    // g2 overwrites aug. No extra ws needed.
    ushort_t* dataB = (ushort_t*)aug;

    cvt_kernel<<<2048, 256, 0, stream>>>(data, dataB);
    prep_kernel<<<dim3(16, 32), 256, 0, stream>>>(mem, memB, memT);
    g1_kernel<<<(M_TOTAL / 128) * (NUMS / 128), 256, 0, stream>>>(dataB, memB, attw);
    topk_kernel<<<M_TOTAL / 32, 256, 0, stream>>>(attw, temporal);
    g2_kernel<<<(M_TOTAL / 128) * (DIM / 128), 256, 0, stream>>>(attw, memT, aug);
}

// Round 10
// 150.332 us; speedup vs baseline: 1.0571x; 1.0099x over previous
//
#include <hip/hip_runtime.h>
#include <stdint.h>

#define M_TOTAL 32768   // B*T
#define NUMS    512
#define DIM     1024
#define TOPK    33

typedef __bf16 bf16_t;
typedef bf16_t bf16x8 __attribute__((ext_vector_type(8)));
typedef float  f32x4  __attribute__((ext_vector_type(4)));
typedef unsigned short ushort_t;

__device__ __forceinline__ ushort_t f2bf(float f) {
    union { float f; uint32_t u; } x; x.f = f;
    uint32_t r = x.u + 0x7FFFu + ((x.u >> 16) & 1u);
    return (ushort_t)(r >> 16);
}
__device__ __forceinline__ float bf2f(uint32_t u) {
    union { uint32_t u; float f; } x; x.u = u << 16;
    return x.f;
}

// global_load_lds: wave-uniform LDS base (HW adds lane*16), per-lane global src
#define GLDS16(g, l) __builtin_amdgcn_global_load_lds( \
    (const __attribute__((address_space(1))) void*)(g), \
    (__attribute__((address_space(3))) void*)(l), 16, 0, 0)

// ---------------------------------------------------------------------------
// cvtprep: blocks 0..2047: data fp32 -> dataB bf16 (streaming);
//          blocks 2048..2559: mem fp32 -> memB bf16 + memT bf16 (transposed).
// ---------------------------------------------------------------------------
__global__ __launch_bounds__(256)
void cvtprep_kernel(const float* __restrict__ data, const float* __restrict__ mem,
                    ushort_t* __restrict__ dataB, ushort_t* __restrict__ memB,
                    ushort_t* __restrict__ memT) {
    __shared__ float tile[32][33];
    const int bid = blockIdx.x;
    const int t   = threadIdx.x;
    if (bid < 2048) {
        const size_t stride = (size_t)2048 * 256 * 8;
        size_t i = ((size_t)bid * 256 + t) * 8;
#pragma unroll
        for (int it = 0; it < 8; ++it, i += stride) {
            const float4 v0 = *(const float4*)(data + i);
            const float4 v1 = *(const float4*)(data + i + 4);
            union { ushort_t us[8]; uint4 v; } pk;
            pk.us[0] = f2bf(v0.x); pk.us[1] = f2bf(v0.y);
            pk.us[2] = f2bf(v0.z); pk.us[3] = f2bf(v0.w);
            pk.us[4] = f2bf(v1.x); pk.us[5] = f2bf(v1.y);
            pk.us[6] = f2bf(v1.z); pk.us[7] = f2bf(v1.w);
            *(uint4*)(dataB + i) = pk.v;
        }
    } else {
        const int pb = bid - 2048;
        const int bi = pb & 15;        // 0..15 (NUMS/32)
        const int bj = pb >> 4;        // 0..31 (DIM/32)
        const int r  = t >> 3;
        const int c4 = (t & 7) * 4;
        const float4 v = *(const float4*)(mem + (size_t)(bi * 32 + r) * DIM + bj * 32 + c4);
        ushort4 b;
        b.x = f2bf(v.x); b.y = f2bf(v.y); b.z = f2bf(v.z); b.w = f2bf(v.w);
        *(ushort4*)(memB + (size_t)(bi * 32 + r) * DIM + bj * 32 + c4) = b;
        tile[r][c4 + 0] = v.x; tile[r][c4 + 1] = v.y;
        tile[r][c4 + 2] = v.z; tile[r][c4 + 3] = v.w;
        __syncthreads();
        ushort4 o;
        o.x = f2bf(tile[c4 + 0][r]); o.y = f2bf(tile[c4 + 1][r]);
        o.z = f2bf(tile[c4 + 2][r]); o.w = f2bf(tile[c4 + 3][r]);
        *(ushort4*)(memT + (size_t)(bj * 32 + r) * NUMS + bi * 32 + c4) = o;
    }
}

// ---------------------------------------------------------------------------
// G1: att = sigmoid(dataB @ memB^T / 32), bf16 store. m97-class structure:
// 128x128, BK=64, SINGLE-buffered 32KB LDS -> up to 5 blocks/CU (TLP hides
// the barrier vmcnt drain — measured better than explicit dbuf, m97 vs m99).
// 256 thr = 4 waves (2x2), wave tile 64x64. Both operands via GLDS.
// Grid 1024; XCD swizzle n-fastest (A-panel shared within one XCD).
// LDS: A@0 (16K), B@16384 (16K). 128B rows, 8 slots: slot s <- chunk s^(r&7).
// ---------------------------------------------------------------------------
__global__ __launch_bounds__(256, 4)
void g1_kernel(const ushort_t* __restrict__ dataB,
               const ushort_t* __restrict__ memB,
               ushort_t* __restrict__ att) {
    __shared__ __align__(16) unsigned char smem[32768];
    const int t    = threadIdx.x;
    const int lane = t & 63;
    const int wid  = t >> 6;      // 0..3
    const int wr   = wid >> 1;    // 0..1
    const int wc   = wid & 1;     // 0..1
    const int wg = (blockIdx.x & 7) * 128 + (blockIdx.x >> 3);
    const int m0 = (wg >> 2) * 128;
    const int n0 = (wg & 3) * 128;

    f32x4 zero = {0.f, 0.f, 0.f, 0.f};
    f32x4 acc[4][4];
#pragma unroll
    for (int m = 0; m < 4; ++m)
#pragma unroll
        for (int n = 0; n < 4; ++n) acc[m][n] = zero;

    const int srcoff = (((lane & 7) ^ (lane >> 3)) & 7) * 8;
    const ushort_t* aS = dataB + (size_t)(m0 + wid * 32 + (lane >> 3)) * DIM + srcoff;
    const ushort_t* bS = memB  + (size_t)(n0 + wid * 32 + (lane >> 3)) * DIM + srcoff;

    for (int tt = 0; tt < 16; ++tt) {
        {
            unsigned char* da = smem + wid * 4096 + lane * 16;
            unsigned char* db = da + 16384;
            const ushort_t* sa = aS + tt * 64;
            const ushort_t* sb = bS + tt * 64;
            GLDS16(sa,            da);        GLDS16(sb,            db);
            GLDS16(sa +  8 * DIM, da + 1024); GLDS16(sb +  8 * DIM, db + 1024);
            GLDS16(sa + 16 * DIM, da + 2048); GLDS16(sb + 16 * DIM, db + 2048);
            GLDS16(sa + 24 * DIM, da + 3072); GLDS16(sb + 24 * DIM, db + 3072);
        }
        __syncthreads();   // drains vmcnt: staged tile visible
#pragma unroll
        for (int ki = 0; ki < 2; ++ki) {
            const int ch = ki * 4 + (lane >> 4);
            bf16x8 af[4], bfr[4];
#pragma unroll
            for (int m = 0; m < 4; ++m) {
                const int row = wr * 64 + m * 16 + (lane & 15);
                af[m] = *(const bf16x8*)(smem + row * 128 + ((ch ^ (row & 7)) << 4));
            }
#pragma unroll
            for (int n = 0; n < 4; ++n) {
                const int col = wc * 64 + n * 16 + (lane & 15);
                bfr[n] = *(const bf16x8*)(smem + 16384 + col * 128 + ((ch ^ (col & 7)) << 4));
            }
#pragma unroll
            for (int m = 0; m < 4; ++m)
#pragma unroll
                for (int n = 0; n < 4; ++n)
                    acc[m][n] = __builtin_amdgcn_mfma_f32_16x16x32_bf16(
                        af[m], bfr[n], acc[m][n], 0, 0, 0);
        }
        __syncthreads();   // all reads done before next stage overwrites
    }

    // ---- epilogue: sigmoid -> bf16 att tile [128][128] in LDS, coalesced store
    ushort_t* lAtt = (ushort_t*)smem;
#pragma unroll
    for (int m = 0; m < 4; ++m)
#pragma unroll
        for (int n = 0; n < 4; ++n)
#pragma unroll
            for (int reg = 0; reg < 4; ++reg) {
                const int row = wr * 64 + m * 16 + (lane >> 4) * 4 + reg;
                const int col = wc * 64 + n * 16 + (lane & 15);
                const float x = acc[m][n][reg] * 0.03125f;   // /sqrt(1024)
                const float s = 1.0f / (1.0f + __expf(-x));
                lAtt[row * 128 + col] = f2bf(s);
            }
    __syncthreads();
    {
        const uint4* lsrc = (const uint4*)lAtt;
#pragma unroll
        for (int i = 0; i < 8; ++i) {
            const int idx = i * 256 + t;
            const int r   = idx >> 4;
            const int c16 = idx & 15;
            *(uint4*)(att + (size_t)(m0 + r) * 512 + n0 + c16 * 8) = lsrc[idx];
        }
    }
}

// ---------------------------------------------------------------------------
// topk: temporal[row] = mean of top-33 of att[row][:] via ballot radix-select
// ---------------------------------------------------------------------------
__global__ __launch_bounds__(256, 8)
void topk_kernel(const ushort_t* __restrict__ att,
                 float* __restrict__ temporal) {
    const int t    = threadIdx.x;
    const int lane = t & 63;
    const int wid  = t >> 6;
    const int base = blockIdx.x * 32 + wid * 8;

    for (int ri = 0; ri < 8; ++ri) {
        const int row = base + ri;
        const uint4 rv = *(const uint4*)(att + (size_t)row * 512 + lane * 8);
        uint32_t u[8];
        u[0] = rv.x & 0xFFFFu; u[1] = rv.x >> 16;
        u[2] = rv.y & 0xFFFFu; u[3] = rv.y >> 16;
        u[4] = rv.z & 0xFFFFu; u[5] = rv.z >> 16;
        u[6] = rv.w & 0xFFFFu; u[7] = rv.w >> 16;
        uint32_t tc = 0;
#pragma unroll
        for (int b = 14; b >= 0; --b) {
            const uint32_t cand = tc | (1u << b);
            int c = 0;
#pragma unroll
            for (int j = 0; j < 8; ++j)
                c += __popcll(__ballot(u[j] >= cand));
            if (c >= TOPK) tc = cand;
        }
        float sgt = 0.f; int cgt = 0;
#pragma unroll
        for (int j = 0; j < 8; ++j) {
            if (u[j] > tc) { sgt += bf2f(u[j]); cgt++; }
        }
#pragma unroll
        for (int off = 32; off >= 1; off >>= 1) {
            sgt += __shfl_xor(sgt, off);
            cgt += __shfl_xor(cgt, off);
        }
        if (lane == 0)
            temporal[row] = (sgt + (float)(TOPK - cgt) * bf2f(tc)) * (1.0f / 33.0f);
    }
}

// ---------------------------------------------------------------------------
// G2: aug = att bf16 @ memT^T. m97-class single-buffer 32KB, 128x128, BK=64,
// 4 waves, XCD-swizzled. LDS: A@0 (16K), B@16384 (16K).
// ---------------------------------------------------------------------------
__global__ __launch_bounds__(256, 4)
void g2_kernel(const ushort_t* __restrict__ att,
               const ushort_t* __restrict__ memT,
               float* __restrict__ aug) {
    __shared__ __align__(16) unsigned char smem[32768];
    const int t    = threadIdx.x;
    const int lane = t & 63;
    const int wid  = t >> 6;
    const int wr   = wid >> 1;
    const int wc   = wid & 1;
    const int wg = (blockIdx.x & 7) * 256 + (blockIdx.x >> 3);
    const int m0 = (wg >> 3) * 128;
    const int n0 = (wg & 7) * 128;

    f32x4 zero = {0.f, 0.f, 0.f, 0.f};
    f32x4 acc[4][4];
#pragma unroll
    for (int m = 0; m < 4; ++m)
#pragma unroll
        for (int n = 0; n < 4; ++n) acc[m][n] = zero;

    const int srcoff = (((lane & 7) ^ (lane >> 3)) & 7) * 8;
    const ushort_t* aS = att  + (size_t)(m0 + wid * 32 + (lane >> 3)) * 512 + srcoff;
    const ushort_t* bS = memT + (size_t)(n0 + wid * 32 + (lane >> 3)) * 512 + srcoff;

    for (int tt = 0; tt < 8; ++tt) {
        {
            unsigned char* da = smem + wid * 4096 + lane * 16;
            unsigned char* db = da + 16384;
            const ushort_t* sa = aS + tt * 64;
            const ushort_t* sb = bS + tt * 64;
            GLDS16(sa,            da);        GLDS16(sb,            db);
            GLDS16(sa +  8 * 512, da + 1024); GLDS16(sb +  8 * 512, db + 1024);
            GLDS16(sa + 16 * 512, da + 2048); GLDS16(sb + 16 * 512, db + 2048);
            GLDS16(sa + 24 * 512, da + 3072); GLDS16(sb + 24 * 512, db + 3072);
        }
        __syncthreads();
#pragma unroll
        for (int ki = 0; ki < 2; ++ki) {
            const int ch = ki * 4 + (lane >> 4);
            bf16x8 af[4], bfr[4];
#pragma unroll
            for (int m = 0; m < 4; ++m) {
                const int row = wr * 64 + m * 16 + (lane & 15);
                af[m] = *(const bf16x8*)(smem + row * 128 + ((ch ^ (row & 7)) << 4));
            }
#pragma unroll
            for (int n = 0; n < 4; ++n) {
                const int col = wc * 64 + n * 16 + (lane & 15);
                bfr[n] = *(const bf16x8*)(smem + 16384 + col * 128 + ((ch ^ (col & 7)) << 4));
            }
#pragma unroll
            for (int m = 0; m < 4; ++m)
#pragma unroll
                for (int n = 0; n < 4; ++n)
                    acc[m][n] = __builtin_amdgcn_mfma_f32_16x16x32_bf16(
                        af[m], bfr[n], acc[m][n], 0, 0, 0);
        }
        __syncthreads();
    }

#pragma unroll
    for (int m = 0; m < 4; ++m)
#pragma unroll
        for (int n = 0; n < 4; ++n)
#pragma unroll
            for (int reg = 0; reg < 4; ++reg) {
                const int row = m0 + wr * 64 + m * 16 + (lane >> 4) * 4 + reg;
                const int col = n0 + wc * 64 + n * 16 + (lane & 15);
                aug[(size_t)row * DIM + col] = acc[m][n][reg];
            }
}

// ---------------------------------------------------------------------------
extern "C" void kernel_launch(void* const* d_in, const int* in_sizes, int n_in,
                              void* d_out, int out_size, void* d_ws, size_t ws_size,
                              hipStream_t stream) {
    const float* data = (const float*)d_in[0];   // [16,2048,1024]
    const float* mem  = (const float*)d_in[1];   // [512,1024]
    float* temporal = (float*)d_out;             // [32768]
    float* aug      = (float*)d_out + M_TOTAL;   // [32768,1024] fp32 (128MB)

    ushort_t* memB = (ushort_t*)d_ws;                    // 1MB
    ushort_t* memT = memB + (size_t)NUMS * DIM;          // 1MB
    ushort_t* attw = memT + (size_t)DIM * NUMS;          // 32MB
    // dataB bf16 (64MB) lives in the aug output region; consumed by g1 before
    // g2 overwrites aug.
    ushort_t* dataB = (ushort_t*)aug;

    cvtprep_kernel<<<2560, 256, 0, stream>>>(data, mem, dataB, memB, memT);
    g1_kernel<<<(M_TOTAL / 128) * (NUMS / 128), 256, 0, stream>>>(dataB, memB, attw);
    topk_kernel<<<M_TOTAL / 32, 256, 0, stream>>>(attw, temporal);
    g2_kernel<<<(M_TOTAL / 128) * (DIM / 128), 256, 0, stream>>>(attw, memT, aug);
}

// Round 11
// 144.871 us; speedup vs baseline: 1.0969x; 1.0377x over previous
//
#include <hip/hip_runtime.h>
#include <stdint.h>

#define M_TOTAL 32768   // B*T
#define NUMS    512
#define DIM     1024
#define TOPK    33

typedef __bf16 bf16_t;
typedef bf16_t bf16x8 __attribute__((ext_vector_type(8)));
typedef float  f32x4  __attribute__((ext_vector_type(4)));
typedef unsigned short ushort_t;

__device__ __forceinline__ ushort_t f2bf(float f) {
    union { float f; uint32_t u; } x; x.f = f;
    uint32_t r = x.u + 0x7FFFu + ((x.u >> 16) & 1u);
    return (ushort_t)(r >> 16);
}
__device__ __forceinline__ float bf2f(uint32_t u) {
    union { uint32_t u; float f; } x; x.u = u << 16;
    return x.f;
}

// global_load_lds: wave-uniform LDS base (HW adds lane*16), per-lane global src
#define GLDS16(g, l) __builtin_amdgcn_global_load_lds( \
    (const __attribute__((address_space(1))) void*)(g), \
    (__attribute__((address_space(3))) void*)(l), 16, 0, 0)

// ---------------------------------------------------------------------------
// cvtprep: blocks 0..2047: data fp32 -> dataB bf16, XCD-ALIGNED: block b
//   (XCD b%8) writes rows (b%8)*4096 + (b>>3)*16 .. +16 — the same rows g1's
//   XCD will consume (g1: XCD x owns m-panels [x*32,(x+1)*32)). Dirty lines
//   stay in the consuming XCD's L2.
// blocks 2048..2559: mem fp32 -> memB bf16 + memT bf16 (transposed).
// ---------------------------------------------------------------------------
__global__ __launch_bounds__(256)
void cvtprep_kernel(const float* __restrict__ data, const float* __restrict__ mem,
                    ushort_t* __restrict__ dataB, ushort_t* __restrict__ memB,
                    ushort_t* __restrict__ memT) {
    __shared__ float tile[32][33];
    const int bid = blockIdx.x;
    const int t   = threadIdx.x;
    if (bid < 2048) {
        const int x = bid & 7;        // XCD
        const int j = bid >> 3;       // 0..255
        size_t i = ((size_t)x * 4096 + (size_t)j * 16) * DIM + t * 8;
#pragma unroll
        for (int it = 0; it < 8; ++it, i += 2048) {
            const float4 v0 = *(const float4*)(data + i);
            const float4 v1 = *(const float4*)(data + i + 4);
            union { ushort_t us[8]; uint4 v; } pk;
            pk.us[0] = f2bf(v0.x); pk.us[1] = f2bf(v0.y);
            pk.us[2] = f2bf(v0.z); pk.us[3] = f2bf(v0.w);
            pk.us[4] = f2bf(v1.x); pk.us[5] = f2bf(v1.y);
            pk.us[6] = f2bf(v1.z); pk.us[7] = f2bf(v1.w);
            *(uint4*)(dataB + i) = pk.v;
        }
    } else {
        const int pb = bid - 2048;
        const int bi = pb & 15;        // 0..15 (NUMS/32)
        const int bj = pb >> 4;        // 0..31 (DIM/32)
        const int r  = t >> 3;
        const int c4 = (t & 7) * 4;
        const float4 v = *(const float4*)(mem + (size_t)(bi * 32 + r) * DIM + bj * 32 + c4);
        ushort4 b;
        b.x = f2bf(v.x); b.y = f2bf(v.y); b.z = f2bf(v.z); b.w = f2bf(v.w);
        *(ushort4*)(memB + (size_t)(bi * 32 + r) * DIM + bj * 32 + c4) = b;
        tile[r][c4 + 0] = v.x; tile[r][c4 + 1] = v.y;
        tile[r][c4 + 2] = v.z; tile[r][c4 + 3] = v.w;
        __syncthreads();
        ushort4 o;
        o.x = f2bf(tile[c4 + 0][r]); o.y = f2bf(tile[c4 + 1][r]);
        o.z = f2bf(tile[c4 + 2][r]); o.w = f2bf(tile[c4 + 3][r]);
        *(ushort4*)(memT + (size_t)(bj * 32 + r) * NUMS + bi * 32 + c4) = o;
    }
}

// ---------------------------------------------------------------------------
// G1: att = sigmoid(dataB @ memB^T / 32), bf16 store. m97-class single-buffer
// 32KB, 128x128, BK=64, 256 thr = 4 waves (2x2), wave tile 64x64, GLDS both.
// Grid 1024; XCD swizzle n-fastest (A-panel shared within one XCD).
// LDS: A@0 (16K), B@16384 (16K). 128B rows, 8 slots: slot s <- chunk s^(r&7).
// ---------------------------------------------------------------------------
__global__ __launch_bounds__(256, 4)
void g1_kernel(const ushort_t* __restrict__ dataB,
               const ushort_t* __restrict__ memB,
               ushort_t* __restrict__ att) {
    __shared__ __align__(16) unsigned char smem[32768];
    const int t    = threadIdx.x;
    const int lane = t & 63;
    const int wid  = t >> 6;      // 0..3
    const int wr   = wid >> 1;    // 0..1
    const int wc   = wid & 1;     // 0..1
    const int wg = (blockIdx.x & 7) * 128 + (blockIdx.x >> 3);
    const int m0 = (wg >> 2) * 128;
    const int n0 = (wg & 3) * 128;

    f32x4 zero = {0.f, 0.f, 0.f, 0.f};
    f32x4 acc[4][4];
#pragma unroll
    for (int m = 0; m < 4; ++m)
#pragma unroll
        for (int n = 0; n < 4; ++n) acc[m][n] = zero;

    const int srcoff = (((lane & 7) ^ (lane >> 3)) & 7) * 8;
    const ushort_t* aS = dataB + (size_t)(m0 + wid * 32 + (lane >> 3)) * DIM + srcoff;
    const ushort_t* bS = memB  + (size_t)(n0 + wid * 32 + (lane >> 3)) * DIM + srcoff;

    for (int tt = 0; tt < 16; ++tt) {
        {
            unsigned char* da = smem + wid * 4096 + lane * 16;
            unsigned char* db = da + 16384;
            const ushort_t* sa = aS + tt * 64;
            const ushort_t* sb = bS + tt * 64;
            GLDS16(sa,            da);        GLDS16(sb,            db);
            GLDS16(sa +  8 * DIM, da + 1024); GLDS16(sb +  8 * DIM, db + 1024);
            GLDS16(sa + 16 * DIM, da + 2048); GLDS16(sb + 16 * DIM, db + 2048);
            GLDS16(sa + 24 * DIM, da + 3072); GLDS16(sb + 24 * DIM, db + 3072);
        }
        __syncthreads();   // drains vmcnt: staged tile visible
#pragma unroll
        for (int ki = 0; ki < 2; ++ki) {
            const int ch = ki * 4 + (lane >> 4);
            bf16x8 af[4], bfr[4];
#pragma unroll
            for (int m = 0; m < 4; ++m) {
                const int row = wr * 64 + m * 16 + (lane & 15);
                af[m] = *(const bf16x8*)(smem + row * 128 + ((ch ^ (row & 7)) << 4));
            }
#pragma unroll
            for (int n = 0; n < 4; ++n) {
                const int col = wc * 64 + n * 16 + (lane & 15);
                bfr[n] = *(const bf16x8*)(smem + 16384 + col * 128 + ((ch ^ (col & 7)) << 4));
            }
#pragma unroll
            for (int m = 0; m < 4; ++m)
#pragma unroll
                for (int n = 0; n < 4; ++n)
                    acc[m][n] = __builtin_amdgcn_mfma_f32_16x16x32_bf16(
                        af[m], bfr[n], acc[m][n], 0, 0, 0);
        }
        __syncthreads();   // all reads done before next stage overwrites
    }

    // ---- epilogue: sigmoid -> bf16 att tile [128][128] in LDS, coalesced store
    ushort_t* lAtt = (ushort_t*)smem;
#pragma unroll
    for (int m = 0; m < 4; ++m)
#pragma unroll
        for (int n = 0; n < 4; ++n)
#pragma unroll
            for (int reg = 0; reg < 4; ++reg) {
                const int row = wr * 64 + m * 16 + (lane >> 4) * 4 + reg;
                const int col = wc * 64 + n * 16 + (lane & 15);
                const float x = acc[m][n][reg] * 0.03125f;   // /sqrt(1024)
                const float s = 1.0f / (1.0f + __expf(-x));
                lAtt[row * 128 + col] = f2bf(s);
            }
    __syncthreads();
    {
        const uint4* lsrc = (const uint4*)lAtt;
#pragma unroll
        for (int i = 0; i < 8; ++i) {
            const int idx = i * 256 + t;
            const int r   = idx >> 4;
            const int c16 = idx & 15;
            *(uint4*)(att + (size_t)(m0 + r) * 512 + n0 + c16 * 8) = lsrc[idx];
        }
    }
}

// ---------------------------------------------------------------------------
// topk: temporal[row] = mean of top-33 of att[row][:] via ballot radix-select.
// 2048 blocks x 4 waves x 4 rows (widened for latency hiding).
// ---------------------------------------------------------------------------
__global__ __launch_bounds__(256, 8)
void topk_kernel(const ushort_t* __restrict__ att,
                 float* __restrict__ temporal) {
    const int t    = threadIdx.x;
    const int lane = t & 63;
    const int wid  = t >> 6;
    const int base = blockIdx.x * 16 + wid * 4;

    for (int ri = 0; ri < 4; ++ri) {
        const int row = base + ri;
        const uint4 rv = *(const uint4*)(att + (size_t)row * 512 + lane * 8);
        uint32_t u[8];
        u[0] = rv.x & 0xFFFFu; u[1] = rv.x >> 16;
        u[2] = rv.y & 0xFFFFu; u[3] = rv.y >> 16;
        u[4] = rv.z & 0xFFFFu; u[5] = rv.z >> 16;
        u[6] = rv.w & 0xFFFFu; u[7] = rv.w >> 16;
        uint32_t tc = 0;
#pragma unroll
        for (int b = 14; b >= 0; --b) {
            const uint32_t cand = tc | (1u << b);
            int c = 0;
#pragma unroll
            for (int j = 0; j < 8; ++j)
                c += __popcll(__ballot(u[j] >= cand));
            if (c >= TOPK) tc = cand;
        }
        float sgt = 0.f; int cgt = 0;
#pragma unroll
        for (int j = 0; j < 8; ++j) {
            if (u[j] > tc) { sgt += bf2f(u[j]); cgt++; }
        }
#pragma unroll
        for (int off = 32; off >= 1; off >>= 1) {
            sgt += __shfl_xor(sgt, off);
            cgt += __shfl_xor(cgt, off);
        }
        if (lane == 0)
            temporal[row] = (sgt + (float)(TOPK - cgt) * bf2f(tc)) * (1.0f / 33.0f);
    }
}

// ---------------------------------------------------------------------------
// G2: aug = att bf16 @ memT^T. m97-class single-buffer 32KB, 128x128, BK=64,
// 4 waves, XCD-swizzled (att handoff from g1 is XCD-aligned).
// ---------------------------------------------------------------------------
__global__ __launch_bounds__(256, 4)
void g2_kernel(const ushort_t* __restrict__ att,
               const ushort_t* __restrict__ memT,
               float* __restrict__ aug) {
    __shared__ __align__(16) unsigned char smem[32768];
    const int t    = threadIdx.x;
    const int lane = t & 63;
    const int wid  = t >> 6;
    const int wr   = wid >> 1;
    const int wc   = wid & 1;
    const int wg = (blockIdx.x & 7) * 256 + (blockIdx.x >> 3);
    const int m0 = (wg >> 3) * 128;
    const int n0 = (wg & 7) * 128;

    f32x4 zero = {0.f, 0.f, 0.f, 0.f};
    f32x4 acc[4][4];
#pragma unroll
    for (int m = 0; m < 4; ++m)
#pragma unroll
        for (int n = 0; n < 4; ++n) acc[m][n] = zero;

    const int srcoff = (((lane & 7) ^ (lane >> 3)) & 7) * 8;
    const ushort_t* aS = att  + (size_t)(m0 + wid * 32 + (lane >> 3)) * 512 + srcoff;
    const ushort_t* bS = memT + (size_t)(n0 + wid * 32 + (lane >> 3)) * 512 + srcoff;

    for (int tt = 0; tt < 8; ++tt) {
        {
            unsigned char* da = smem + wid * 4096 + lane * 16;
            unsigned char* db = da + 16384;
            const ushort_t* sa = aS + tt * 64;
            const ushort_t* sb = bS + tt * 64;
            GLDS16(sa,            da);        GLDS16(sb,            db);
            GLDS16(sa +  8 * 512, da + 1024); GLDS16(sb +  8 * 512, db + 1024);
            GLDS16(sa + 16 * 512, da + 2048); GLDS16(sb + 16 * 512, db + 2048);
            GLDS16(sa + 24 * 512, da + 3072); GLDS16(sb + 24 * 512, db + 3072);
        }
        __syncthreads();
#pragma unroll
        for (int ki = 0; ki < 2; ++ki) {
            const int ch = ki * 4 + (lane >> 4);
            bf16x8 af[4], bfr[4];
#pragma unroll
            for (int m = 0; m < 4; ++m) {
                const int row = wr * 64 + m * 16 + (lane & 15);
                af[m] = *(const bf16x8*)(smem + row * 128 + ((ch ^ (row & 7)) << 4));
            }
#pragma unroll
            for (int n = 0; n < 4; ++n) {
                const int col = wc * 64 + n * 16 + (lane & 15);
                bfr[n] = *(const bf16x8*)(smem + 16384 + col * 128 + ((ch ^ (col & 7)) << 4));
            }
#pragma unroll
            for (int m = 0; m < 4; ++m)
#pragma unroll
                for (int n = 0; n < 4; ++n)
                    acc[m][n] = __builtin_amdgcn_mfma_f32_16x16x32_bf16(
                        af[m], bfr[n], acc[m][n], 0, 0, 0);
        }
        __syncthreads();
    }

#pragma unroll
    for (int m = 0; m < 4; ++m)
#pragma unroll
        for (int n = 0; n < 4; ++n)
#pragma unroll
            for (int reg = 0; reg < 4; ++reg) {
                const int row = m0 + wr * 64 + m * 16 + (lane >> 4) * 4 + reg;
                const int col = n0 + wc * 64 + n * 16 + (lane & 15);
                aug[(size_t)row * DIM + col] = acc[m][n][reg];
            }
}

// ---------------------------------------------------------------------------
extern "C" void kernel_launch(void* const* d_in, const int* in_sizes, int n_in,
                              void* d_out, int out_size, void* d_ws, size_t ws_size,
                              hipStream_t stream) {
    const float* data = (const float*)d_in[0];   // [16,2048,1024]
    const float* mem  = (const float*)d_in[1];   // [512,1024]
    float* temporal = (float*)d_out;             // [32768]
    float* aug      = (float*)d_out + M_TOTAL;   // [32768,1024] fp32 (128MB)

    ushort_t* memB = (ushort_t*)d_ws;                    // 1MB
    ushort_t* memT = memB + (size_t)NUMS * DIM;          // 1MB
    ushort_t* attw = memT + (size_t)DIM * NUMS;          // 32MB
    // dataB bf16 (64MB) lives in the aug output region; consumed by g1 before
    // g2 overwrites aug.
    ushort_t* dataB = (ushort_t*)aug;

    cvtprep_kernel<<<2560, 256, 0, stream>>>(data, mem, dataB, memB, memT);
    g1_kernel<<<(M_TOTAL / 128) * (NUMS / 128), 256, 0, stream>>>(dataB, memB, attw);
    topk_kernel<<<M_TOTAL / 16, 256, 0, stream>>>(attw, temporal);
    g2_kernel<<<(M_TOTAL / 128) * (DIM / 128), 256, 0, stream>>>(attw, memT, aug);
}